// Round 6
// baseline (917.806 us; speedup 1.0000x reference)
//
#include <hip/hip_runtime.h>

#define NB 128
#define NS 256
#define NI 64
#define NH 128
#define NL 64
#define NG 384  // 3*NH

typedef _Float16 f16;
typedef __attribute__((ext_vector_type(2))) _Float16 f16x2;

__device__ __forceinline__ float fast_tanh(float x) {
    float e = __expf(2.0f * x);
    return 1.0f - 2.0f / (e + 1.0f);
}
__device__ __forceinline__ float fast_sig(float x) {
    return 1.0f / (1.0f + __expf(-x));
}
// pair reduce via DPP quad_perm [1,0,3,2] (xor 1) — pure VALU
__device__ __forceinline__ float red1(float a) {
    int ai = __builtin_bit_cast(int, a);
    int bi = __builtin_amdgcn_update_dpp(0, ai, 0xB1, 0xF, 0xF, true);
    return a + __builtin_bit_cast(float, bi);
}
__device__ __forceinline__ float fdot2(f16x2 a, f16x2 b, float c) {
#if __has_builtin(__builtin_amdgcn_fdot2)
    return __builtin_amdgcn_fdot2(a, b, c, false);
#else
    return c + (float)a.x * (float)b.x + (float)a.y * (float)b.y;
#endif
}
__device__ __forceinline__ f16x2 bc16(unsigned int u) {
    return __builtin_bit_cast(f16x2, u);
}
// LDS-only workgroup barrier: does NOT drain vmcnt (global prefetch stays in flight)
__device__ __forceinline__ void sync_lds() {
    asm volatile("s_waitcnt lgkmcnt(0)" ::: "memory");
    __builtin_amdgcn_s_barrier();
    asm volatile("" ::: "memory");
}

// ---- f16 weight tables (pre-rounded once by prep_kernel) ----
__device__ __align__(16) f16 g_W1h[NH * NH];
__device__ __align__(16) f16 g_W2h[NH * NH];
__device__ __align__(16) f16 g_W12h[NH * NH];
__device__ __align__(16) f16 g_Whhh[3 * NH * NH];
__device__ __align__(16) f16 g_Whh2h[3 * NH * NH];
__device__ float g_w1b2[NH];
__device__ float g_whhb2[3 * NH];

// ---------------------------------------------------------------------------
// GX precompute: gx[s][b][j] = b_ih[j] + sum_c x[b][s][c] * W_ih[j][c]
// ---------------------------------------------------------------------------
__global__ __launch_bounds__(384)
void gx_kernel(const float* __restrict__ x, const float* __restrict__ W_ih,
               const float* __restrict__ b_ih, float* __restrict__ gx)
{
    const int s = blockIdx.x;
    const int j = threadIdx.x;
    __shared__ __align__(16) float xs[NB * NI];
    for (int idx = j; idx < NB * NI; idx += 384) {
        int bb = idx >> 6, cc = idx & 63;
        xs[idx] = x[(bb * NS + s) * NI + cc];
    }
    float w[64];
#pragma unroll
    for (int c = 0; c < 64; c += 4)
        *(float4*)&w[c] = *(const float4*)&W_ih[j * NI + c];
    const float bj = b_ih[j];
    __syncthreads();
    for (int bb = 0; bb < NB; bb++) {
        const float* xr = xs + bb * NI;
        float a0 = 0.f, a1 = 0.f, a2 = 0.f, a3 = 0.f;
#pragma unroll
        for (int c = 0; c < 64; c += 4) {
            a0 = fmaf(w[c + 0], xr[c + 0], a0);
            a1 = fmaf(w[c + 1], xr[c + 1], a1);
            a2 = fmaf(w[c + 2], xr[c + 2], a2);
            a3 = fmaf(w[c + 3], xr[c + 3], a3);
        }
        gx[((size_t)s * NB + bb) * NG + j] = ((a0 + a1) + (a2 + a3)) + bj;
    }
}

// ---------------------------------------------------------------------------
// Setup (fp32 math, then round to f16): W12=W1@W2, Whh2=Whh@W2, W1b2, Whhb2,
// plus f16 copies of W1, W2, Whh.
// ---------------------------------------------------------------------------
__global__ __launch_bounds__(128)
void prep_kernel(const float* __restrict__ W1, const float* __restrict__ Whh,
                 const float* __restrict__ W2, const float* __restrict__ b2)
{
    const int i = blockIdx.x;   // 0..511
    const int j = threadIdx.x;  // 0..127
    __shared__ float rowA[NH];
    __shared__ float red[NH];
    const float* src = (i < NH) ? (W1 + i * NH) : (Whh + (size_t)(i - NH) * NH);
    rowA[j] = src[j];
    __syncthreads();
    float acc = 0.f;
    for (int k = 0; k < NH; k++) acc = fmaf(rowA[k], W2[k * NH + j], acc);
    if (i < NH) {
        g_W12h[i * NH + j] = (f16)acc;
        g_W1h[i * NH + j]  = (f16)rowA[j];
        g_W2h[i * NH + j]  = (f16)W2[i * NH + j];
    } else {
        g_Whh2h[(size_t)(i - NH) * NH + j] = (f16)acc;
        g_Whhh[(size_t)(i - NH) * NH + j]  = (f16)rowA[j];
    }
    red[j] = rowA[j] * b2[j];
    __syncthreads();
    for (int off = 64; off > 0; off >>= 1) {
        if (j < off) red[j] += red[j + off];
        __syncthreads();
    }
    if (j == 0) {
        if (i < NH) g_w1b2[i] = red[0];
        else        g_whhb2[i - NH] = red[0];
    }
}

// ---------------------------------------------------------------------------
// dot helpers: 256 threads, 2 lanes per row. Lane p owns cols [64p, 64p+64)
// (bytes [128p, 128p+128) of the 256B f16 row) as 8 x 16B chunks.
// Broadcast LDS reads: per instruction only 2 distinct 16B addresses
// (one per p), each 32-way broadcast -> conflict-free.
// ---------------------------------------------------------------------------
#define DOT1(W, SRC, OUT)                                                      \
    {                                                                          \
        float a0_ = 0.f, a1_ = 0.f, a2_ = 0.f, a3_ = 0.f;                      \
        _Pragma("unroll") for (int j = 0; j < 8; j++)                          \
        {                                                                      \
            uint4 v_ = *(const uint4*)((const unsigned char*)(SRC) + pbase + 16 * j); \
            a0_ = fdot2(W[4 * j + 0], bc16(v_.x), a0_);                        \
            a1_ = fdot2(W[4 * j + 1], bc16(v_.y), a1_);                        \
            a2_ = fdot2(W[4 * j + 2], bc16(v_.z), a2_);                        \
            a3_ = fdot2(W[4 * j + 3], bc16(v_.w), a3_);                        \
        }                                                                      \
        OUT = red1((a0_ + a1_) + (a2_ + a3_));                                 \
    }

#define DOT2S(WA, WB, SRC, OA, OB)                                             \
    {                                                                          \
        float a0_ = 0.f, a1_ = 0.f, a2_ = 0.f, a3_ = 0.f;                      \
        float b0_ = 0.f, b1_ = 0.f, b2_ = 0.f, b3_ = 0.f;                      \
        _Pragma("unroll") for (int j = 0; j < 8; j++)                          \
        {                                                                      \
            uint4 v_ = *(const uint4*)((const unsigned char*)(SRC) + pbase + 16 * j); \
            a0_ = fdot2(WA[4 * j + 0], bc16(v_.x), a0_);                       \
            a1_ = fdot2(WA[4 * j + 1], bc16(v_.y), a1_);                       \
            a2_ = fdot2(WA[4 * j + 2], bc16(v_.z), a2_);                       \
            a3_ = fdot2(WA[4 * j + 3], bc16(v_.w), a3_);                       \
            b0_ = fdot2(WB[4 * j + 0], bc16(v_.x), b0_);                       \
            b1_ = fdot2(WB[4 * j + 1], bc16(v_.y), b1_);                       \
            b2_ = fdot2(WB[4 * j + 2], bc16(v_.z), b2_);                       \
            b3_ = fdot2(WB[4 * j + 3], bc16(v_.w), b3_);                       \
        }                                                                      \
        OA = red1((a0_ + a1_) + (a2_ + a3_));                                  \
        OB = red1((b0_ + b1_) + (b2_ + b3_));                                  \
    }

#define DOT2D(WA, SA, WB, SB, OA, OB)                                          \
    {                                                                          \
        float a0_ = 0.f, a1_ = 0.f, a2_ = 0.f, a3_ = 0.f;                      \
        float b0_ = 0.f, b1_ = 0.f, b2_ = 0.f, b3_ = 0.f;                      \
        _Pragma("unroll") for (int j = 0; j < 8; j++)                          \
        {                                                                      \
            uint4 v_ = *(const uint4*)((const unsigned char*)(SA) + pbase + 16 * j); \
            uint4 u_ = *(const uint4*)((const unsigned char*)(SB) + pbase + 16 * j); \
            a0_ = fdot2(WA[4 * j + 0], bc16(v_.x), a0_);                       \
            a1_ = fdot2(WA[4 * j + 1], bc16(v_.y), a1_);                       \
            a2_ = fdot2(WA[4 * j + 2], bc16(v_.z), a2_);                       \
            a3_ = fdot2(WA[4 * j + 3], bc16(v_.w), a3_);                       \
            b0_ = fdot2(WB[4 * j + 0], bc16(u_.x), b0_);                       \
            b1_ = fdot2(WB[4 * j + 1], bc16(u_.y), b1_);                       \
            b2_ = fdot2(WB[4 * j + 2], bc16(u_.z), b2_);                       \
            b3_ = fdot2(WB[4 * j + 3], bc16(u_.w), b3_);                       \
        }                                                                      \
        OA = red1((a0_ + a1_) + (a2_ + a3_));                                  \
        OB = red1((b0_ + b1_) + (b2_ + b3_));                                  \
    }

#define DOT4S(WA, WB, WC, WD, SRC, OA, OB, OC, OD)                             \
    {                                                                          \
        float a0_ = 0.f, a1_ = 0.f, b0_ = 0.f, b1_ = 0.f;                      \
        float c0_ = 0.f, c1_ = 0.f, d0_ = 0.f, d1_ = 0.f;                      \
        _Pragma("unroll") for (int j = 0; j < 8; j++)                          \
        {                                                                      \
            uint4 v_ = *(const uint4*)((const unsigned char*)(SRC) + pbase + 16 * j); \
            a0_ = fdot2(WA[4 * j + 0], bc16(v_.x), a0_);                       \
            a1_ = fdot2(WA[4 * j + 1], bc16(v_.y), a1_);                       \
            a0_ = fdot2(WA[4 * j + 2], bc16(v_.z), a0_);                       \
            a1_ = fdot2(WA[4 * j + 3], bc16(v_.w), a1_);                       \
            b0_ = fdot2(WB[4 * j + 0], bc16(v_.x), b0_);                       \
            b1_ = fdot2(WB[4 * j + 1], bc16(v_.y), b1_);                       \
            b0_ = fdot2(WB[4 * j + 2], bc16(v_.z), b0_);                       \
            b1_ = fdot2(WB[4 * j + 3], bc16(v_.w), b1_);                       \
            c0_ = fdot2(WC[4 * j + 0], bc16(v_.x), c0_);                       \
            c1_ = fdot2(WC[4 * j + 1], bc16(v_.y), c1_);                       \
            c0_ = fdot2(WC[4 * j + 2], bc16(v_.z), c0_);                       \
            c1_ = fdot2(WC[4 * j + 3], bc16(v_.w), c1_);                       \
            d0_ = fdot2(WD[4 * j + 0], bc16(v_.x), d0_);                       \
            d1_ = fdot2(WD[4 * j + 1], bc16(v_.y), d1_);                       \
            d0_ = fdot2(WD[4 * j + 2], bc16(v_.z), d0_);                       \
            d1_ = fdot2(WD[4 * j + 3], bc16(v_.w), d1_);                       \
        }                                                                      \
        OA = red1(a0_ + a1_);                                                  \
        OB = red1(b0_ + b1_);                                                  \
        OC = red1(c0_ + c1_);                                                  \
        OD = red1(d0_ + d1_);                                                  \
    }

#define LOADW(DST, BASE)                                                       \
    {                                                                          \
        _Pragma("unroll") for (int j = 0; j < 8; j++)                          \
        {                                                                      \
            uint4 v_ = *(const uint4*)((const unsigned char*)(BASE) + pbase + 16 * j); \
            DST[4 * j + 0] = bc16(v_.x); DST[4 * j + 1] = bc16(v_.y);          \
            DST[4 * j + 2] = bc16(v_.z); DST[4 * j + 3] = bc16(v_.w);          \
        }                                                                      \
    }

// ---------------------------------------------------------------------------
// Main recurrence: 1 WG / batch element, 256 threads (2 lanes per row),
// 4 waves at 1 wave/SIMD (512-reg budget), 9 serial stages / step.
// Weights 9 x 32 f16x2 = 288 regs resident (unified VGPR/AGPR file).
// ---------------------------------------------------------------------------
__global__ __launch_bounds__(256, 1)
void rnn_kernel(const float* __restrict__ times, const float* __restrict__ b_hh,
                const float* __restrict__ b1, const float* __restrict__ b2,
                const float* __restrict__ W_mean, const float* __restrict__ b_mean,
                const float* __restrict__ W_logvar, const float* __restrict__ b_logvar,
                const float* __restrict__ gx,
                const float* __restrict__ x, const float* __restrict__ W_ih,
                const float* __restrict__ b_ih,
                const int use_gx,
                float* __restrict__ out)
{
    const int b = blockIdx.x;
    const int t = threadIdx.x;    // 0..255
    const int r = t >> 1;         // row 0..127
    const int p = t & 1;          // half 0/1
    const int pbase = 128 * p;    // byte offset of this lane's half-row

    __shared__ __align__(16) f16 shHh[NH], shUh[NH], shAh[NH];
    __shared__ float shT[NS];
    __shared__ __align__(16) float shGX[NG], shX[NI], shHf[NH];

    // ---- register-resident packed-f16 weights (literal indices only) ----
    f16x2 w1p[32], w2p[32], w12p[32];
    f16x2 wh0p[32], wh1p[32], wh2p[32];
    f16x2 ws0p[32], ws1p[32], ws2p[32];
    LOADW(w1p,  g_W1h  + r * NH);
    LOADW(w2p,  g_W2h  + r * NH);
    LOADW(w12p, g_W12h + r * NH);
    LOADW(wh0p, g_Whhh + (0 * NH + r) * NH);
    LOADW(wh1p, g_Whhh + (1 * NH + r) * NH);
    LOADW(wh2p, g_Whhh + (2 * NH + r) * NH);
    LOADW(ws0p, g_Whh2h + (size_t)(0 * NH + r) * NH);
    LOADW(ws1p, g_Whh2h + (size_t)(1 * NH + r) * NH);
    LOADW(ws2p, g_Whh2h + (size_t)(2 * NH + r) * NH);

    const float b1r = b1[r], b2r = b2[r];
    const float bh0 = b_hh[r], bh1 = b_hh[NH + r], bh2 = b_hh[2 * NH + r];
    const float w1b2r = g_w1b2[r];
    const float wb0 = g_whhb2[r], wb1 = g_whhb2[NH + r], wb2 = g_whhb2[2 * NH + r];

    if (t < NS) shT[t] = times[t];
    if (t < NH) shHh[t] = (f16)0.f;
    float h = 0.f;  // fp32 h carried in registers (both lanes of the pair)
    __syncthreads();

    // gx double-buffer: step si's values loaded one iteration ahead.
    float gxr = 0.f, gxz = 0.f, gxn = 0.f;
    if (use_gx) {
        const float* g = gx + ((size_t)(NS - 1) * NB + b) * NG;
        gxr = g[r]; gxz = g[NH + r]; gxn = g[2 * NH + r];
    }

    for (int si = 0; si < NS; ++si) {
        const int seq = NS - 1 - si;
        const float dt = (si == 0) ? 0.f : (shT[seq] - shT[seq + 1]);
        const float dts = 0.5f * dt;  // substep dt (N_SUB=2)
        const float a2 = 0.5f * dts;
        const float a6 = dts * (1.f / 6.f);

        // issue NEXT step's gx loads now (vmcnt NOT drained by sync_lds, so
        // these stay in flight under the whole step's 9 stages).
        float gnr = 0.f, gnz = 0.f, gnn = 0.f;
        if (use_gx) {
            const int seqn = (seq > 0) ? (seq - 1) : 0;
            const float* g = gx + ((size_t)seqn * NB + b) * NG;
            gnr = g[r]; gnz = g[NH + r]; gnn = g[2 * NH + r];
        } else {
            if (t < NI) shX[t] = x[(b * NS + seq) * NI + t];
            __syncthreads();
            for (int idx = t; idx < NG; idx += 256) {
                const float* wr = W_ih + idx * NI;
                float a = 0.f;
#pragma unroll
                for (int cc = 0; cc < NI; cc += 4) {
                    float4 w4 = *(const float4*)(wr + cc);
                    a = fmaf(w4.x, shX[cc + 0], a);
                    a = fmaf(w4.y, shX[cc + 1], a);
                    a = fmaf(w4.z, shX[cc + 2], a);
                    a = fmaf(w4.w, shX[cc + 3], a);
                }
                shGX[idx] = a + b_ih[idx];
            }
            __syncthreads();
        }

        // ======== substep A ========
        float z1a, u, S, m;
        // stage 1: z1 = W1 h + b1
        DOT1(w1p, shHh, z1a);
        z1a += b1r;
        u = fast_tanh(z1a);
        if (p == 0) shUh[r] = (f16)u;
        S = u;
        sync_lds();
        // stage 2
        DOT1(w12p, shUh, m);
        u = fast_tanh(z1a + a2 * (m + w1b2r));
        if (p == 0) shUh[r] = (f16)u;
        S += 2.f * u;
        sync_lds();
        // stage 3
        DOT1(w12p, shUh, m);
        u = fast_tanh(z1a + a2 * (m + w1b2r));
        if (p == 0) shUh[r] = (f16)u;
        S += 2.f * u;
        sync_lds();
        // stage 4 (k4 uses full dts)
        DOT1(w12p, shUh, m);
        u = fast_tanh(z1a + dts * (m + w1b2r));
        S += u;
        if (p == 0) shUh[r] = (f16)S;  // S becomes the stage-5 source
        sync_lds();
        // stage 5: hA = h + a6 W2 S + dts b2 ; z1b = z1a + a6 W12 S + dts W1b2
        float mA, mB;
        DOT2S(w2p, w12p, shUh, mA, mB);
        const float hA = h + a6 * mA + dts * b2r;
        const float z1b = z1a + a6 * mB + dts * w1b2r;
        u = fast_tanh(z1b);
        if (p == 0) { shAh[r] = (f16)hA; shUh[r] = (f16)u; }
        float S2 = u;
        sync_lds();

        // ======== substep B (+ Whh·hA folded in as pair-matvecs) ========
        float g0, g1, g2;
        // stage 6
        DOT2D(w12p, shUh, wh0p, shAh, m, g0);
        u = fast_tanh(z1b + a2 * (m + w1b2r));
        if (p == 0) shUh[r] = (f16)u;
        S2 += 2.f * u;
        sync_lds();
        // stage 7
        DOT2D(w12p, shUh, wh1p, shAh, m, g1);
        u = fast_tanh(z1b + a2 * (m + w1b2r));
        if (p == 0) shUh[r] = (f16)u;
        S2 += 2.f * u;
        sync_lds();
        // stage 8
        DOT2D(w12p, shUh, wh2p, shAh, m, g2);
        u = fast_tanh(z1b + dts * (m + w1b2r));
        S2 += u;
        if (p == 0) shUh[r] = (f16)S2;  // S2 becomes the stage-9 source
        sync_lds();
        // stage 9: 4-matvec over S2 ; GRU (computed on both lanes)
        float n0, n1, n2, n3;
        DOT4S(w2p, ws0p, ws1p, ws2p, shUh, n0, n1, n2, n3);
        const float hB = hA + a6 * n0 + dts * b2r;
        const float rh = g0 + a6 * n1 + dts * wb0 + bh0;
        const float zh = g1 + a6 * n2 + dts * wb1 + bh1;
        const float nh = g2 + a6 * n3 + dts * wb2 + bh2;
        float rx, zx, nx;
        if (use_gx) { rx = gxr; zx = gxz; nx = gxn; }
        else        { rx = shGX[r]; zx = shGX[NH + r]; nx = shGX[2 * NH + r]; }
        const float rr = fast_sig(rx + rh);
        const float zz = fast_sig(zx + zh);
        const float nn = fast_tanh(nx + rr * nh);
        h = (1.f - zz) * nn + zz * hB;
        if (p == 0) shHh[r] = (f16)h;
        // rotate gx double-buffer
        gxr = gnr; gxz = gnz; gxn = gnn;
        sync_lds();
    }

    // ---- epilogue: full-precision heads from fp32 h ----
    if (p == 0) shHf[r] = h;
    __syncthreads();
    const int sel = r >> 6;
    const int l = r & 63;
    const float* Wf = sel ? W_logvar : W_mean;
    const int hc0 = 64 * p;
    float a0 = 0.f, a1 = 0.f;
#pragma unroll
    for (int jj = 0; jj < 16; jj++) {
        float4 w4 = *(const float4*)&Wf[l * NH + hc0 + 4 * jj];
        float4 h4 = *(const float4*)(shHf + hc0 + 4 * jj);
        a0 = fmaf(w4.x, h4.x, a0);
        a1 = fmaf(w4.y, h4.y, a1);
        a0 = fmaf(w4.z, h4.z, a0);
        a1 = fmaf(w4.w, h4.w, a1);
    }
    float acc = red1(a0 + a1);
    if (p == 0) {
        const float bias = sel ? b_logvar[l] : b_mean[l];
        out[sel * (NB * NL) + b * NL + l] = acc + bias;
    }
}

extern "C" void kernel_launch(void* const* d_in, const int* in_sizes, int n_in,
                              void* d_out, int out_size, void* d_ws, size_t ws_size,
                              hipStream_t stream)
{
    const float* x        = (const float*)d_in[0];
    const float* times    = (const float*)d_in[1];
    const float* W_ih     = (const float*)d_in[2];
    const float* W_hh     = (const float*)d_in[3];
    const float* b_ih     = (const float*)d_in[4];
    const float* b_hh     = (const float*)d_in[5];
    const float* W1       = (const float*)d_in[6];
    const float* b1       = (const float*)d_in[7];
    const float* W2       = (const float*)d_in[8];
    const float* b2       = (const float*)d_in[9];
    const float* W_mean   = (const float*)d_in[10];
    const float* b_mean   = (const float*)d_in[11];
    const float* W_logvar = (const float*)d_in[12];
    const float* b_logvar = (const float*)d_in[13];
    float* out = (float*)d_out;

    float* gxbuf = (float*)d_ws;
    const size_t need = (size_t)NS * NB * NG * sizeof(float);  // ~50.3 MB
    const int use_gx = (d_ws != nullptr && ws_size >= need) ? 1 : 0;

    if (use_gx) {
        gx_kernel<<<NS, 384, 0, stream>>>(x, W_ih, b_ih, gxbuf);
    }
    prep_kernel<<<512, 128, 0, stream>>>(W1, W_hh, W2, b2);
    rnn_kernel<<<NB, 256, 0, stream>>>(times, b_hh, b1, b2,
                                       W_mean, b_mean, W_logvar, b_logvar,
                                       gxbuf, x, W_ih, b_ih, use_gx, out);
}